// Round 9
// baseline (52.739 us; speedup 1.0000x reference)
//
#include <hip/hip_runtime.h>
#include <hip/hip_bf16.h>
#include <math.h>

// HyperbolicDistanceHead: out[r][c] = -(2/sqrt(c))*atanh(clip(sqrt(c)*||mobius(-x,p)||, 0, 1-1e-5))
// B=128, C=4096, D=1024, c=0.5.  SINGLE kernel, two phases + device-scope grid barrier:
//  Phase 1 (blocks 0..127): row r=bid of x -> bf16 MFMA-A-fragment order in ws
//      ([panel][t][lane] 16B words) + exact fp32 x2[r]. LDS transpose.
//  Barrier: ws counter; workers __threadfence + release-add; all blocks acquire-spin.
//      Residency guaranteed: __launch_bounds__(256,2) + 10.6 KB LDS -> 2 blocks/CU.
//  Phase 2 (all 512 blocks): 64 rows x 16 cols; A coalesced bf16 frags global->reg
//      (no LDS); p fp32->reg->cvt->XOR-swz LDS dbuf (p2 fused); BK=128 x 8 chunks,
//      1 barrier/chunk, T14 issue-early/write-late; fused Poincare epilogue.

#define DDIM 1024
#define CDIM 4096
#define BDIM 128

using f32x4  = __attribute__((ext_vector_type(4))) float;
using bf16x8 = __attribute__((ext_vector_type(8))) short;

__device__ inline ushort toBfU(float f) {
  __hip_bfloat16 h = __float2bfloat16(f);
  return *reinterpret_cast<ushort*>(&h);
}

__global__ __launch_bounds__(256, 2) void hyper_sync(
    const float* __restrict__ x, const float* __restrict__ p,
    ushort* __restrict__ xb, float* __restrict__ x2g,
    unsigned* __restrict__ cnt, float* __restrict__ out) {
  __shared__ __align__(16) ushort xrow[1024];     // phase-1 transpose bounce (2 KB)
  __shared__ float rpart[4];
  __shared__ __align__(16) char ps[2][4096];      // [buf][16 cols][256 B]
  __shared__ float p2s[16];
  __shared__ float x2l[64];

  const int tid  = threadIdx.x;
  const int lane = tid & 63;
  const int w    = __builtin_amdgcn_readfirstlane(tid >> 6);  // 0..3
  const int r15  = lane & 15, g = lane >> 4;
  const int bid  = blockIdx.x;

  // bijective XCD chunk swizzle (512 % 8 == 0)
  const int swz = ((bid & 7) << 6) | (bid >> 3);
  const int cg = swz >> 1, rg = swz & 1;
  const int rbase = rg * 64, cbase = cg * 16;

  // phase-2 p staging map: col = tid>>4, k-octet o = tid&15
  const int col = tid >> 4, o = tid & 15;
  const float* gp = p + (size_t)(cbase + col) * DDIM + o * 8;
  const int pw = col * 256 + ((o ^ (col & 7)) << 4);
  // phase-2 A fragment stream: panel q = rg*4 + w
  const char* ga = (const char*)xb + ((size_t)(rg * 4 + w) * 2048 + lane) * 16;

  f32x4 acc = {0.f, 0.f, 0.f, 0.f};
  float p2p = 0.f;
  f32x4 pa0, pa1;
  bf16x8 aA[2][4];

#define ISSUE_A(c, ph)                                                         \
  { _Pragma("unroll")                                                          \
    for (int s = 0; s < 4; ++s)                                                \
      aA[ph][s] = *(const bf16x8*)(ga + ((c) * 4 + s) * 1024); }

#define ISSUE_P(c)                                                             \
  { pa0 = *(const f32x4*)(gp + (c) * 128);                                     \
    pa1 = *(const f32x4*)(gp + (c) * 128 + 4); }

#define WRITE_P(buf)                                                           \
  { p2p = fmaf(pa0[0], pa0[0], p2p); p2p = fmaf(pa0[1], pa0[1], p2p);          \
    p2p = fmaf(pa0[2], pa0[2], p2p); p2p = fmaf(pa0[3], pa0[3], p2p);          \
    p2p = fmaf(pa1[0], pa1[0], p2p); p2p = fmaf(pa1[1], pa1[1], p2p);          \
    p2p = fmaf(pa1[2], pa1[2], p2p); p2p = fmaf(pa1[3], pa1[3], p2p);          \
    bf16x8 _t;                                                                 \
    _t[0] = (short)toBfU(pa0[0]); _t[1] = (short)toBfU(pa0[1]);                \
    _t[2] = (short)toBfU(pa0[2]); _t[3] = (short)toBfU(pa0[3]);                \
    _t[4] = (short)toBfU(pa1[0]); _t[5] = (short)toBfU(pa1[1]);                \
    _t[6] = (short)toBfU(pa1[2]); _t[7] = (short)toBfU(pa1[3]);                \
    *(bf16x8*)&ps[buf][pw] = _t; }

#define COMPUTE(buf, ph)                                                       \
  { _Pragma("unroll")                                                          \
    for (int s = 0; s < 4; ++s) {                                              \
      const int off = ((s * 4 + g) ^ (r15 & 7)) << 4;                          \
      const bf16x8 b = *(const bf16x8*)&ps[buf][r15 * 256 + off];              \
      acc = __builtin_amdgcn_mfma_f32_16x16x32_bf16(aA[ph][s], b, acc, 0, 0, 0); \
    } }

  // ---- p chunk 0: issue early so HBM latency hides under phase 1 / spin
  ISSUE_P(0)

  // ---- phase 1: blocks 0..127 fragment one x-row each
  if (bid < BDIM) {
    const int r = bid;
    const f32x4 v = *(const f32x4*)(x + (size_t)r * DDIM + tid * 4);
    float a = v[0] * v[0];
    a = fmaf(v[1], v[1], a); a = fmaf(v[2], v[2], a); a = fmaf(v[3], v[3], a);
    ushort4 ov = { toBfU(v[0]), toBfU(v[1]), toBfU(v[2]), toBfU(v[3]) };
    *(ushort4*)&xrow[tid * 4] = ov;
    #pragma unroll
    for (int off = 32; off > 0; off >>= 1) a += __shfl_xor(a, off, 64);
    if (lane == 0) rpart[w] = a;
    __syncthreads();
    if (tid < 128) {
      // word (t = tid>>2, g2 = tid&3) of row r: elems [tid*8 .. +7]
      const bf16x8 wv = *(const bf16x8*)&xrow[tid * 8];
      const size_t word = (size_t)(r >> 4) * 2048 + (tid >> 2) * 64 + (tid & 3) * 16 + (r & 15);
      *(bf16x8*)((char*)xb + word * 16) = wv;
    }
    if (tid == 0) x2g[r] = rpart[0] + rpart[1] + rpart[2] + rpart[3];
    __threadfence();                      // each thread: stores -> agent scope
    __syncthreads();                      // all threads' fenced stores before release
    if (tid == 0)
      __hip_atomic_fetch_add(cnt, 1u, __ATOMIC_RELEASE, __HIP_MEMORY_SCOPE_AGENT);
  }

  // ---- stage p chunk 0 while waiting (block-local LDS, independent of barrier)
  WRITE_P(0)

  // ---- grid barrier: wait for all 128 worker blocks
  if (tid == 0) {
    while (__hip_atomic_load(cnt, __ATOMIC_ACQUIRE, __HIP_MEMORY_SCOPE_AGENT) < 128u)
      __builtin_amdgcn_s_sleep(8);
  }
  __syncthreads();

  // ---- phase 2 ----
  if (tid < 64) x2l[tid] = x2g[rbase + tid];
  ISSUE_A(0, 0)

  #pragma unroll
  for (int c = 0; c < 8; ++c) {
    __syncthreads();                 // publish ps[c&1] (+ x2l on c==0)
    if (c < 7) { ISSUE_A(c + 1, (c + 1) & 1) ISSUE_P(c + 1) }
    COMPUTE(c & 1, c & 1)
    if (c < 7) WRITE_P((c + 1) & 1)
  }

  // ---- p2 reduce: 16-lane groups (lanes sharing a col)
  p2p += __shfl_xor(p2p, 8, 64);
  p2p += __shfl_xor(p2p, 4, 64);
  p2p += __shfl_xor(p2p, 2, 64);
  p2p += __shfl_xor(p2p, 1, 64);
  if ((lane & 15) == 0) p2s[col] = p2p;
  __syncthreads();

  // ---- epilogue: closed-form Poincare distance, c = 0.5
  const float p2 = p2s[r15];
  #pragma unroll
  for (int i = 0; i < 4; ++i) {
    // C-frag: col = lane&15, row = (lane>>4)*4 + i (verified m89 mapping)
    const int  rloc = (w << 4) + (g << 2) + i;     // block-local row
    const float dot = acc[i];                      // <x,p>; mdot = -dot
    const float x2  = x2l[rloc];
    const float A   = 1.0f - dot + 0.5f  * p2;     // 1 + 2c*mdot + c*p2
    const float Bc  = 1.0f - 0.5f * x2;            // 1 - c*x2
    const float den = 1.0f - dot + 0.25f * x2 * p2;
    float num2 = A * A * x2 - 2.0f * A * Bc * dot + Bc * Bc * p2;
    float m2   = fmaxf(num2, 0.0f) / fmaxf(den * den, 1e-15f);
    float arg  = fminf(0.7071067811865476f * sqrtf(m2 + 1e-15f), 0.99999f);
    out[(size_t)(rbase + rloc) * CDIM + cbase + r15] =
        -1.4142135623730951f * __logf((1.0f + arg) / (1.0f - arg));
  }
}

extern "C" void kernel_launch(void* const* d_in, const int* in_sizes, int n_in,
                              void* d_out, int out_size, void* d_ws, size_t ws_size,
                              hipStream_t stream) {
  const float* x = (const float*)d_in[0];   // [128,1024] fp32
  const float* p = (const float*)d_in[1];   // [4096,1024] fp32
  float* out = (float*)d_out;               // [128,4096] fp32

  // ws: xb frags [8][2048][16B] = 262144 | x2[128] f32 = 512 | cnt u32
  ushort*   xb  = (ushort*)d_ws;
  float*    x2  = (float*)((char*)d_ws + 262144);
  unsigned* cnt = (unsigned*)((char*)d_ws + 262656);

  hipMemsetAsync(cnt, 0, 4, stream);        // reset barrier counter (capture-legal)
  hyper_sync<<<dim3(512), dim3(256), 0, stream>>>(x, p, xb, x2, cnt, out);
}

// Round 10
// 51.653 us; speedup vs baseline: 1.0210x; 1.0210x over previous
//
#include <hip/hip_runtime.h>
#include <hip/hip_bf16.h>
#include <math.h>

// HyperbolicDistanceHead: out[r][c] = -(2/sqrt(c))*atanh(clip(sqrt(c)*||mobius(-x,p)||, 0, 1-1e-5))
// B=128, C=4096, D=1024, c=0.5.  SINGLE kernel, grid-sync, CHUNKLESS phase 2:
//  Phase 1 (blocks 0..127): x row bid -> bf16 A-fragment words in ws + exact x2.
//  Barrier: RELEASE atomic-add (r9-proven); poll is an ACQUIRE atomic RMW
//      (fetch_add 0) -- RMWs always hit the coherent point (fixes r9's 45us
//      stale-L2 spin). All 512 blocks co-resident: 256 thr, <=256 VGPR, 35 KB LDS.
//  Phase 2: block = 64 rows x 16 cols. p staged whole-K in ONE burst (fp32->reg
//      ->cvt->XOR-swz LDS, p2 fused) -> ONE barrier, no per-chunk drains. A = 32
//      coalesced bf16x8 words -> 128 VGPRs (no LDS). 32x {ds_read B, MFMA}.

#define DDIM 1024
#define CDIM 4096
#define BDIM 128

using f32x4  = __attribute__((ext_vector_type(4))) float;
using bf16x8 = __attribute__((ext_vector_type(8))) short;

__device__ inline ushort toBfU(float f) {
  __hip_bfloat16 h = __float2bfloat16(f);
  return *reinterpret_cast<ushort*>(&h);
}

__global__ __launch_bounds__(256, 2) void hyper_sync2(
    const float* __restrict__ x, const float* __restrict__ p,
    ushort* __restrict__ xb, float* __restrict__ x2g,
    unsigned* __restrict__ cnt, float* __restrict__ out) {
  __shared__ __align__(16) ushort xrow[1024];   // phase-1 bounce (2 KB)
  __shared__ float rpart[4];
  __shared__ __align__(16) char ps[16 * 2048];  // 32 KB: whole-K p tile, bf16, swz
  __shared__ float p2s[16];
  __shared__ float x2l[64];

  const int tid  = threadIdx.x;
  const int lane = tid & 63;
  const int w    = __builtin_amdgcn_readfirstlane(tid >> 6);  // 0..3
  const int r15  = lane & 15, g = lane >> 4;
  const int bid  = blockIdx.x;

  // bijective XCD chunk swizzle (512 % 8 == 0)
  const int swz = ((bid & 7) << 6) | (bid >> 3);
  const int cg = swz >> 1, rg = swz & 1;
  const int rbase = rg * 64, cbase = cg * 16;

  // ---- phase 1: blocks 0..127 fragment one x-row each (r9-proven layout)
  if (bid < BDIM) {
    const int r = bid;
    const f32x4 v = *(const f32x4*)(x + (size_t)r * DDIM + tid * 4);
    float a = v[0] * v[0];
    a = fmaf(v[1], v[1], a); a = fmaf(v[2], v[2], a); a = fmaf(v[3], v[3], a);
    ushort4 ov = { toBfU(v[0]), toBfU(v[1]), toBfU(v[2]), toBfU(v[3]) };
    *(ushort4*)&xrow[tid * 4] = ov;
    #pragma unroll
    for (int off = 32; off > 0; off >>= 1) a += __shfl_xor(a, off, 64);
    if (lane == 0) rpart[w] = a;
    __syncthreads();
    if (tid < 128) {
      const bf16x8 wv = *(const bf16x8*)&xrow[tid * 8];
      const size_t word = (size_t)(r >> 4) * 2048 + (tid >> 2) * 64 + (tid & 3) * 16 + (r & 15);
      *(bf16x8*)((char*)xb + word * 16) = wv;
    }
    if (tid == 0) x2g[r] = rpart[0] + rpart[1] + rpart[2] + rpart[3];
    __threadfence();
    __syncthreads();
    if (tid == 0)
      __hip_atomic_fetch_add(cnt, 1u, __ATOMIC_RELEASE, __HIP_MEMORY_SCOPE_AGENT);
  }

  // ---- p staging, whole K, one burst (independent of phase 1; overlaps it)
  const int c16 = tid >> 4, j = tid & 15;     // col 0..15, k-slot 0..15
  const float* pgc = p + (size_t)(cbase + c16) * DDIM;
  f32x4 pa[16];
  #pragma unroll
  for (int i = 0; i < 8; ++i) {
    pa[2 * i]     = *(const f32x4*)(pgc + (j + i * 16) * 8);
    pa[2 * i + 1] = *(const f32x4*)(pgc + (j + i * 16) * 8 + 4);
  }
  float p2p = 0.f;
  #pragma unroll
  for (int i = 0; i < 16; ++i) {
    p2p = fmaf(pa[i][0], pa[i][0], p2p); p2p = fmaf(pa[i][1], pa[i][1], p2p);
    p2p = fmaf(pa[i][2], pa[i][2], p2p); p2p = fmaf(pa[i][3], pa[i][3], p2p);
  }
  #pragma unroll
  for (int i = 0; i < 8; ++i) {
    bf16x8 t;
    t[0] = (short)toBfU(pa[2*i][0]);   t[1] = (short)toBfU(pa[2*i][1]);
    t[2] = (short)toBfU(pa[2*i][2]);   t[3] = (short)toBfU(pa[2*i][3]);
    t[4] = (short)toBfU(pa[2*i+1][0]); t[5] = (short)toBfU(pa[2*i+1][1]);
    t[6] = (short)toBfU(pa[2*i+1][2]); t[7] = (short)toBfU(pa[2*i+1][3]);
    *(bf16x8*)&ps[c16 * 2048 + ((((j + i * 16) << 4)) ^ ((c16 & 7) << 4))] = t;
  }
  // p2 reduce within 16-lane group (lane&15 == j)
  p2p += __shfl_xor(p2p, 8, 64);
  p2p += __shfl_xor(p2p, 4, 64);
  p2p += __shfl_xor(p2p, 2, 64);
  p2p += __shfl_xor(p2p, 1, 64);
  if ((lane & 15) == 0) p2s[c16] = p2p;

  // ---- grid barrier: ACQUIRE RMW poll (always coherent), staggered backoff
  if (tid == 0) {
    while (__hip_atomic_fetch_add(cnt, 0u, __ATOMIC_ACQUIRE,
                                  __HIP_MEMORY_SCOPE_AGENT) < 128u) {
      __builtin_amdgcn_s_sleep(32);
      if (bid & 1) __builtin_amdgcn_s_sleep(16);
    }
  }
  __syncthreads();   // broadcast barrier-done; publishes ps + p2s block-wide

  // ---- A fragments: 32 coalesced words -> 128 VGPRs (no LDS)
  const char* ga = (const char*)xb + ((size_t)(rg * 4 + w) * 2048 + lane) * 16;
  bf16x8 aA[32];
  #pragma unroll
  for (int t = 0; t < 32; ++t) aA[t] = *(const bf16x8*)(ga + t * 1024);

  if (tid < 64) x2l[tid] = x2g[rbase + tid];
  __syncthreads();   // publish x2l

  // ---- MFMA loop: 32 x {swizzled ds_read B, MFMA}; A from registers
  f32x4 acc = {0.f, 0.f, 0.f, 0.f};
  const int bbase = r15 * 2048;
  const int bswz  = (lane & 7) << 4;
  #pragma unroll
  for (int t = 0; t < 32; ++t) {
    const bf16x8 b = *(const bf16x8*)&ps[bbase + ((t * 64 + (g << 4)) ^ bswz)];
    acc = __builtin_amdgcn_mfma_f32_16x16x32_bf16(aA[t], b, acc, 0, 0, 0);
  }

  // ---- epilogue: closed-form Poincare distance, c = 0.5
  const float p2 = p2s[r15];
  #pragma unroll
  for (int i = 0; i < 4; ++i) {
    // C-frag: col = lane&15, row = (lane>>4)*4 + i (verified m89 mapping)
    const int  rloc = (w << 4) + (g << 2) + i;     // block-local row
    const float dot = acc[i];                      // <x,p>; mdot = -dot
    const float x2  = x2l[rloc];
    const float A   = 1.0f - dot + 0.5f  * p2;     // 1 + 2c*mdot + c*p2
    const float Bc  = 1.0f - 0.5f * x2;            // 1 - c*x2
    const float den = 1.0f - dot + 0.25f * x2 * p2;
    float num2 = A * A * x2 - 2.0f * A * Bc * dot + Bc * Bc * p2;
    float m2   = fmaxf(num2, 0.0f) / fmaxf(den * den, 1e-15f);
    float arg  = fminf(0.7071067811865476f * sqrtf(m2 + 1e-15f), 0.99999f);
    out[(size_t)(rbase + rloc) * CDIM + cbase + r15] =
        -1.4142135623730951f * __logf((1.0f + arg) / (1.0f - arg));
  }
}

extern "C" void kernel_launch(void* const* d_in, const int* in_sizes, int n_in,
                              void* d_out, int out_size, void* d_ws, size_t ws_size,
                              hipStream_t stream) {
  const float* x = (const float*)d_in[0];   // [128,1024] fp32
  const float* p = (const float*)d_in[1];   // [4096,1024] fp32
  float* out = (float*)d_out;               // [128,4096] fp32

  // ws: xb frags [8][2048][16B] = 262144 | x2[128] f32 = 512 | cnt u32
  ushort*   xb  = (ushort*)d_ws;
  float*    x2  = (float*)((char*)d_ws + 262144);
  unsigned* cnt = (unsigned*)((char*)d_ws + 262656);

  hipMemsetAsync(cnt, 0, 4, stream);        // reset barrier counter (capture-legal)
  hyper_sync2<<<dim3(512), dim3(256), 0, stream>>>(x, p, xb, x2, cnt, out);
}

// Round 11
// 15.051 us; speedup vs baseline: 3.5040x; 3.4319x over previous
//
#include <hip/hip_runtime.h>
#include <hip/hip_bf16.h>
#include <math.h>

// HyperbolicDistanceHead: out[r][c] = -(2/sqrt(c))*atanh(clip(sqrt(c)*||mobius(-x,p)||, 0, 1-1e-5))
// B=128, C=4096, D=1024, c=0.5.  Single launch, no workspace.
// 512 blocks x 256 thr (2/CU); block = 32 rows x 32 cols; wave kq = FULL 32x32 tile
// on k-slices [c*128+kq*32,+32) -> per chunk/wave: 4 ds_read_b128 + 4 MFMA (2x2
// quads, A/B reused x2). Depth-2 reg pipeline: LOAD(c+2); COMPUTE(c); WRITE(c+1);
// barrier. fp32->reg->cvt->XOR-swz LDS both operands; exact x2/p2 from pre-cvt
// fp32. K-partials combined via 16KB LDS reuse; verified m89 C-layout epilogue.

#define DDIM 1024
#define CDIM 4096

using f32x4  = __attribute__((ext_vector_type(4))) float;
using bf16x8 = __attribute__((ext_vector_type(8))) short;

__device__ inline ushort toBfU(float f) {
  __hip_bfloat16 h = __float2bfloat16(f);
  return *reinterpret_cast<ushort*>(&h);
}

__global__ __launch_bounds__(256, 3) void hyper_k32(
    const float* __restrict__ x, const float* __restrict__ p,
    float* __restrict__ out) {
  __shared__ __align__(16) char xs[2][8192];   // [buf][32 rows][256 B], XOR-swz
  __shared__ __align__(16) char ps[2][8192];   // [buf][32 cols][256 B], XOR-swz
  __shared__ float x2s[32], p2s[32];

  const int tid  = threadIdx.x;
  const int lane = tid & 63;
  const int w    = __builtin_amdgcn_readfirstlane(tid >> 6);  // 0..3 = kq = quad
  const int r15  = lane & 15, g = lane >> 4;

  // bijective XCD chunk swizzle (512 % 8 == 0): 4 consecutive-on-XCD blocks share cg
  const int bid  = blockIdx.x;
  const int swz  = ((bid & 7) << 6) | (bid >> 3);
  const int rg   = swz & 3, cg = swz >> 2;
  const int rbase = rg * 32, cbase = cg * 32;

  // staging: thread covers row/col srow = tid>>3, floats (tid&7)*16 .. +15 per chunk
  const int srow = tid >> 3;
  const float* gx = x + (size_t)(rbase + srow) * DDIM + ((tid & 7) << 4);
  const float* gp = p + (size_t)(cbase + srow) * DDIM + ((tid & 7) << 4);
  const int ssw = (srow & 7) << 4;
  const int sb0 = srow * 256 + ((((tid & 7) << 5) +  0) ^ ssw);
  const int sb1 = srow * 256 + ((((tid & 7) << 5) + 16) ^ ssw);

  float sx = 0.f, sp = 0.f;
  f32x4 acc00 = {0.f,0.f,0.f,0.f}, acc01 = acc00, acc10 = acc00, acc11 = acc00;
  f32x4 xa0[4], pa0[4], xa1[4], pa1[4];

#define LOADS(S, c)                                                           \
  { _Pragma("unroll")                                                         \
    for (int i = 0; i < 4; ++i) {                                             \
      xa##S[i] = *(const f32x4*)(gx + (c) * 128 + i * 4);                     \
      pa##S[i] = *(const f32x4*)(gp + (c) * 128 + i * 4);                     \
    } }

#define SSQ4(v) (fmaf((v)[3],(v)[3],fmaf((v)[2],(v)[2],fmaf((v)[1],(v)[1],(v)[0]*(v)[0]))))

#define PACKW(a, b, dst)                                                      \
  { bf16x8 _t;                                                                \
    _t[0]=(short)toBfU((a)[0]); _t[1]=(short)toBfU((a)[1]);                   \
    _t[2]=(short)toBfU((a)[2]); _t[3]=(short)toBfU((a)[3]);                   \
    _t[4]=(short)toBfU((b)[0]); _t[5]=(short)toBfU((b)[1]);                   \
    _t[6]=(short)toBfU((b)[2]); _t[7]=(short)toBfU((b)[3]);                   \
    *(bf16x8*)(dst) = _t; }

#define WRITES(S, BUF)                                                        \
  { sx += SSQ4(xa##S[0]) + SSQ4(xa##S[1]) + SSQ4(xa##S[2]) + SSQ4(xa##S[3]);  \
    sp += SSQ4(pa##S[0]) + SSQ4(pa##S[1]) + SSQ4(pa##S[2]) + SSQ4(pa##S[3]);  \
    PACKW(xa##S[0], xa##S[1], &xs[BUF][sb0])                                  \
    PACKW(xa##S[2], xa##S[3], &xs[BUF][sb1])                                  \
    PACKW(pa##S[0], pa##S[1], &ps[BUF][sb0])                                  \
    PACKW(pa##S[2], pa##S[3], &ps[BUF][sb1])                                  \
  }

#define COMPUTE(BUF)                                                          \
  { const int ba = ((w << 6) + (g << 4)) ^ ((r15 & 7) << 4);                  \
    const bf16x8 A0 = *(const bf16x8*)&xs[BUF][r15 * 256 + ba];               \
    const bf16x8 A1 = *(const bf16x8*)&xs[BUF][(16 + r15) * 256 + ba];        \
    const bf16x8 Bq0 = *(const bf16x8*)&ps[BUF][r15 * 256 + ba];              \
    const bf16x8 Bq1 = *(const bf16x8*)&ps[BUF][(16 + r15) * 256 + ba];       \
    acc00 = __builtin_amdgcn_mfma_f32_16x16x32_bf16(A0, Bq0, acc00, 0, 0, 0); \
    acc10 = __builtin_amdgcn_mfma_f32_16x16x32_bf16(A1, Bq0, acc10, 0, 0, 0); \
    acc01 = __builtin_amdgcn_mfma_f32_16x16x32_bf16(A0, Bq1, acc01, 0, 0, 0); \
    acc11 = __builtin_amdgcn_mfma_f32_16x16x32_bf16(A1, Bq1, acc11, 0, 0, 0); \
  }

  // ---- prologue: chunks 0,1 -> reg sets 0,1; chunk 0 -> buf 0
  LOADS(0, 0)
  LOADS(1, 1)
  WRITES(0, 0)
  __syncthreads();

  // ---- main: 8 chunks of BK=128; depth-2, one barrier per chunk
  #pragma unroll
  for (int c = 0; c < 8; ++c) {
    if (c < 6) { if ((c & 1) == 0) LOADS(0, c + 2) else LOADS(1, c + 2) }
    if ((c & 1) == 0) COMPUTE(0) else COMPUTE(1)
    if (c < 7) { if ((c & 1) == 0) WRITES(1, 1) else WRITES(0, 0) }
    __syncthreads();
  }

  // ---- exact norms: 8 staging threads per row/col (consecutive lanes)
  sx += __shfl_xor(sx, 1, 64); sx += __shfl_xor(sx, 2, 64); sx += __shfl_xor(sx, 4, 64);
  sp += __shfl_xor(sp, 1, 64); sp += __shfl_xor(sp, 2, 64); sp += __shfl_xor(sp, 4, 64);
  if ((lane & 7) == 0) { x2s[srow] = sx; p2s[srow] = sp; }

  // ---- combine K-slice partials: reuse xs (16 KB), slot = (kq*4 + quad)
  f32x4* cb = (f32x4*)xs;
  cb[(w * 4 + 0) * 64 + lane] = acc00;   // quad 0: rows 0-15,  cols 0-15
  cb[(w * 4 + 1) * 64 + lane] = acc10;   // quad 1: rows 16-31, cols 0-15
  cb[(w * 4 + 2) * 64 + lane] = acc01;   // quad 2: rows 0-15,  cols 16-31
  cb[(w * 4 + 3) * 64 + lane] = acc11;   // quad 3: rows 16-31, cols 16-31
  __syncthreads();

  f32x4 fa = cb[(0 * 4 + w) * 64 + lane];
  fa += cb[(1 * 4 + w) * 64 + lane];
  fa += cb[(2 * 4 + w) * 64 + lane];
  fa += cb[(3 * 4 + w) * 64 + lane];

  // ---- epilogue: wave w owns quad w; C-frag col = lane&15, row = g*4+i (m89)
  const int qr = w & 1, qc = w >> 1;
  const float p2 = p2s[qc * 16 + r15];
  #pragma unroll
  for (int i = 0; i < 4; ++i) {
    const int  rloc = qr * 16 + g * 4 + i;        // block-local row
    const float dot = fa[i];                      // <x,p>; mdot = -dot
    const float x2  = x2s[rloc];
    const float A   = 1.0f - dot + 0.5f  * p2;    // 1 + 2c*mdot + c*p2
    const float Bc  = 1.0f - 0.5f * x2;           // 1 - c*x2
    const float den = 1.0f - dot + 0.25f * x2 * p2;
    float num2 = A * A * x2 - 2.0f * A * Bc * dot + Bc * Bc * p2;
    float m2   = fmaxf(num2, 0.0f) / fmaxf(den * den, 1e-15f);
    float arg  = fminf(0.7071067811865476f * sqrtf(m2 + 1e-15f), 0.99999f);
    out[(size_t)(rbase + rloc) * CDIM + cbase + qc * 16 + r15] =
        -1.4142135623730951f * __logf((1.0f + arg) / (1.0f - arg));
  }
}

extern "C" void kernel_launch(void* const* d_in, const int* in_sizes, int n_in,
                              void* d_out, int out_size, void* d_ws, size_t ws_size,
                              hipStream_t stream) {
  const float* x = (const float*)d_in[0];   // [128,1024] fp32
  const float* p = (const float*)d_in[1];   // [4096,1024] fp32
  float* out = (float*)d_out;               // [128,4096] fp32
  hyper_k32<<<dim3(512), dim3(256), 0, stream>>>(x, p, out);
}

// Round 12
// 14.777 us; speedup vs baseline: 3.5689x; 1.0185x over previous
//
#include <hip/hip_runtime.h>
#include <hip/hip_bf16.h>
#include <math.h>

// HyperbolicDistanceHead: out[r][c] = -(2/sqrt(c))*atanh(clip(sqrt(c)*||mobius(-x,p)||, 0, 1-1e-5))
// B=128, C=4096, D=1024, c=0.5.  Single launch, no workspace.
// 512 blocks x 256 thr (2/CU); block = 32 rows x 32 cols; wave kq handles the full
// 32x32 tile on k-slice [c*128 + kq*32, +32) -> 4 ds_read_b128 + 4 MFMA per chunk.
// SINGLE staging reg set + r7-proven schedule {LOADS(c+1); COMPUTE(c); WRITES(c+1);
// barrier} (T14), launch_bounds(256,2) -> no VGPR squeeze (r11's spill suspect).
// fp32->reg->cvt->XOR-swz LDS both operands; exact x2/p2 from pre-cvt fp32;
// K-partials combined via LDS reuse; verified m89 C-layout epilogue.

#define DDIM 1024
#define CDIM 4096

using f32x4  = __attribute__((ext_vector_type(4))) float;
using bf16x8 = __attribute__((ext_vector_type(8))) short;

__device__ inline ushort toBfU(float f) {
  __hip_bfloat16 h = __float2bfloat16(f);
  return *reinterpret_cast<ushort*>(&h);
}

__global__ __launch_bounds__(256, 2) void hyper_k32b(
    const float* __restrict__ x, const float* __restrict__ p,
    float* __restrict__ out) {
  __shared__ __align__(16) char xs[2][8192];   // [buf][32 rows][256 B], XOR-swz
  __shared__ __align__(16) char ps[2][8192];   // [buf][32 cols][256 B], XOR-swz
  __shared__ float x2s[32], p2s[32];

  const int tid  = threadIdx.x;
  const int lane = tid & 63;
  const int w    = __builtin_amdgcn_readfirstlane(tid >> 6);  // 0..3 = kq = quad
  const int r15  = lane & 15, g = lane >> 4;

  // bijective XCD chunk swizzle (512 % 8 == 0): 4 same-cg rowgroup blocks co-XCD
  const int bid  = blockIdx.x;
  const int swz  = ((bid & 7) << 6) | (bid >> 3);
  const int rg   = swz & 3, cg = swz >> 2;
  const int rbase = rg * 32, cbase = cg * 32;

  // staging: thread covers row/col srow = tid>>3, floats (tid&7)*16 .. +15 per chunk
  const int srow = tid >> 3;
  const float* gx = x + (size_t)(rbase + srow) * DDIM + ((tid & 7) << 4);
  const float* gp = p + (size_t)(cbase + srow) * DDIM + ((tid & 7) << 4);
  const int ssw = (srow & 7) << 4;
  const int sb0 = srow * 256 + ((((tid & 7) << 5) +  0) ^ ssw);
  const int sb1 = srow * 256 + ((((tid & 7) << 5) + 16) ^ ssw);

  float sx = 0.f, sp = 0.f;
  f32x4 acc00 = {0.f,0.f,0.f,0.f}, acc01 = acc00, acc10 = acc00, acc11 = acc00;
  f32x4 xa[4], pa[4];   // ONE staging set (32 VGPR)

#define LOADS(c)                                                              \
  { _Pragma("unroll")                                                         \
    for (int i = 0; i < 4; ++i) {                                             \
      xa[i] = *(const f32x4*)(gx + (c) * 128 + i * 4);                        \
      pa[i] = *(const f32x4*)(gp + (c) * 128 + i * 4);                        \
    } }

#define SSQ4(v) (fmaf((v)[3],(v)[3],fmaf((v)[2],(v)[2],fmaf((v)[1],(v)[1],(v)[0]*(v)[0]))))

#define PACKW(a, b, dst)                                                      \
  { bf16x8 _t;                                                                \
    _t[0]=(short)toBfU((a)[0]); _t[1]=(short)toBfU((a)[1]);                   \
    _t[2]=(short)toBfU((a)[2]); _t[3]=(short)toBfU((a)[3]);                   \
    _t[4]=(short)toBfU((b)[0]); _t[5]=(short)toBfU((b)[1]);                   \
    _t[6]=(short)toBfU((b)[2]); _t[7]=(short)toBfU((b)[3]);                   \
    *(bf16x8*)(dst) = _t; }

#define WRITES(BUF)                                                           \
  { sx += SSQ4(xa[0]) + SSQ4(xa[1]) + SSQ4(xa[2]) + SSQ4(xa[3]);              \
    sp += SSQ4(pa[0]) + SSQ4(pa[1]) + SSQ4(pa[2]) + SSQ4(pa[3]);              \
    PACKW(xa[0], xa[1], &xs[BUF][sb0])                                        \
    PACKW(xa[2], xa[3], &xs[BUF][sb1])                                        \
    PACKW(pa[0], pa[1], &ps[BUF][sb0])                                        \
    PACKW(pa[2], pa[3], &ps[BUF][sb1])                                        \
  }

#define COMPUTE(BUF)                                                          \
  { const int ba = ((w << 6) + (g << 4)) ^ ((r15 & 7) << 4);                  \
    const bf16x8 A0  = *(const bf16x8*)&xs[BUF][r15 * 256 + ba];              \
    const bf16x8 A1  = *(const bf16x8*)&xs[BUF][(16 + r15) * 256 + ba];       \
    const bf16x8 Bq0 = *(const bf16x8*)&ps[BUF][r15 * 256 + ba];              \
    const bf16x8 Bq1 = *(const bf16x8*)&ps[BUF][(16 + r15) * 256 + ba];       \
    acc00 = __builtin_amdgcn_mfma_f32_16x16x32_bf16(A0, Bq0, acc00, 0, 0, 0); \
    acc10 = __builtin_amdgcn_mfma_f32_16x16x32_bf16(A1, Bq0, acc10, 0, 0, 0); \
    acc01 = __builtin_amdgcn_mfma_f32_16x16x32_bf16(A0, Bq1, acc01, 0, 0, 0); \
    acc11 = __builtin_amdgcn_mfma_f32_16x16x32_bf16(A1, Bq1, acc11, 0, 0, 0); \
  }

  // ---- prologue: chunk 0 -> regs -> buf 0
  LOADS(0)
  WRITES(0)
  __syncthreads();

  // ---- main: 8 chunks of BK=128; issue-early (T14), one barrier per chunk
  #pragma unroll
  for (int c = 0; c < 8; ++c) {
    if (c < 7) LOADS(c + 1)          // global fp32 -> regs; hides under COMPUTE
    COMPUTE(c & 1)
    if (c < 7) WRITES((c + 1) & 1)   // cvt + ds_write into the freed buffer
    __syncthreads();                 // publish buf (c+1)&1
  }

  // ---- exact norms: 8 staging threads per row/col (consecutive lanes)
  sx += __shfl_xor(sx, 1, 64); sx += __shfl_xor(sx, 2, 64); sx += __shfl_xor(sx, 4, 64);
  sp += __shfl_xor(sp, 1, 64); sp += __shfl_xor(sp, 2, 64); sp += __shfl_xor(sp, 4, 64);
  if ((lane & 7) == 0) { x2s[srow] = sx; p2s[srow] = sp; }

  // ---- combine K-slice partials: reuse xs (16 KB), slot = (kq*4 + quad)
  f32x4* cb = (f32x4*)xs;
  cb[(w * 4 + 0) * 64 + lane] = acc00;   // quad 0: rows 0-15,  cols 0-15
  cb[(w * 4 + 1) * 64 + lane] = acc10;   // quad 1: rows 16-31, cols 0-15
  cb[(w * 4 + 2) * 64 + lane] = acc01;   // quad 2: rows 0-15,  cols 16-31
  cb[(w * 4 + 3) * 64 + lane] = acc11;   // quad 3: rows 16-31, cols 16-31
  __syncthreads();

  f32x4 fa = cb[(0 * 4 + w) * 64 + lane];
  fa += cb[(1 * 4 + w) * 64 + lane];
  fa += cb[(2 * 4 + w) * 64 + lane];
  fa += cb[(3 * 4 + w) * 64 + lane];

  // ---- epilogue: wave w owns quad w; C-frag col = lane&15, row = g*4+i (m89)
  const int qr = w & 1, qc = w >> 1;
  const float p2 = p2s[qc * 16 + r15];
  #pragma unroll
  for (int i = 0; i < 4; ++i) {
    const int  rloc = qr * 16 + g * 4 + i;        // block-local row
    const float dot = fa[i];                      // <x,p>; mdot = -dot
    const float x2  = x2s[rloc];
    const float A   = 1.0f - dot + 0.5f  * p2;    // 1 + 2c*mdot + c*p2
    const float Bc  = 1.0f - 0.5f * x2;           // 1 - c*x2
    const float den = 1.0f - dot + 0.25f * x2 * p2;
    float num2 = A * A * x2 - 2.0f * A * Bc * dot + Bc * Bc * p2;
    float m2   = fmaxf(num2, 0.0f) / fmaxf(den * den, 1e-15f);
    float arg  = fminf(0.7071067811865476f * sqrtf(m2 + 1e-15f), 0.99999f);
    out[(size_t)(rbase + rloc) * CDIM + cbase + qc * 16 + r15] =
        -1.4142135623730951f * __logf((1.0f + arg) / (1.0f - arg));
  }
}

extern "C" void kernel_launch(void* const* d_in, const int* in_sizes, int n_in,
                              void* d_out, int out_size, void* d_ws, size_t ws_size,
                              hipStream_t stream) {
  const float* x = (const float*)d_in[0];   // [128,1024] fp32
  const float* p = (const float*)d_in[1];   // [4096,1024] fp32
  float* out = (float*)d_out;               // [128,4096] fp32
  hyper_k32b<<<dim3(512), dim3(256), 0, stream>>>(x, p, out);
}